// Round 7
// baseline (1684.400 us; speedup 1.0000x reference)
//
#include <hip/hip_runtime.h>
#include <hip/hip_bf16.h>
#include <math.h>

#define DIM 1024
#define BATCH 16384
#define NLAYER 6

typedef __bf16 bf16_t;
typedef __attribute__((ext_vector_type(8))) __bf16 bf16x8;
typedef __attribute__((ext_vector_type(4))) float f32x4;

__device__ __forceinline__ float fast_tanh(float x) {
  x = fminf(9.f, fmaxf(-9.f, x));
  const float e = __expf(x + x);
  return (e - 1.f) * __builtin_amdgcn_rcpf(e + 1.f);
}

__device__ __forceinline__ float bf2f(unsigned short u) {
  return __uint_as_float(((unsigned int)u) << 16);
}

// ---------------------------------------------------------------------------
// GEMM: C[m,n] = sum_k A[m,k] * W[n,k]  (A [BATCH x DIM] bf16, W [DIM x DIM])
// MODE 0: Tb = bf16( fast_tanh(scale[m]*C + b1[n]) )
// MODE 1: hb[m,n] = cf.w*hb_old + C + b2[n] + ce*e[n] + cc*c[n] + cn*nn[n]
//         + per-row stats partials (plain f32x4 store, NO atomics)
// MODE 2: MODE1 math but writes fp32 outF ONLY (final layer; hb is dead)
//
// CACHE-DIRECT K-loop (R6 experiment, resubmitted after infra failure):
// NO LDS, NO barriers. Each lane loads its MFMA fragments straight from
// global: aF[i] = 16 rows x 64B = 16 full cache lines per instruction.
// W (2MB) is L2-resident; A-panel (512KB) has 8x cross-block reuse,
// captured in-L2 via XCD-grouped block mapping (the 8 column-blocks of a
// row-panel are consecutive on one XCD). Cost: 2x in-block fragment
// duplication (~1GB L2/GEMM = 29us at 34.5TB/s); benefit: zero sync -
// compiler pipelines 16 loads vs 32 MFMA per K-step freely.
// Rationale: R0/R5 structure is sync-bound (MfmaUtil 21%, HBM 25%, VALU 20%,
// all pipes idle); R1-R3 barrier'd restructures all regressed.
// R3 lesson: no global atomics (line-granular RMW write-through).
// R4 lesson: rows are covered by TWO waves (column halves wn=0/64), so each
// column half needs its OWN partial slot: part[row][16], slot = byi*2+(w>>1).
// ---------------------------------------------------------------------------
template <int MODE>
__global__ __launch_bounds__(256, 3) void gemm_kernel(
    const bf16_t* __restrict__ A, const bf16_t* __restrict__ W,
    const float* __restrict__ bias, bf16_t* __restrict__ outB,
    float* __restrict__ outF, const f32x4* __restrict__ coef,
    const f32x4* __restrict__ colpack, const float* __restrict__ scaleArr,
    const bf16_t* __restrict__ hbIn, float* __restrict__ part) {
  const int tid = threadIdx.x;
  const int w = tid >> 6;
  const int lane = tid & 63;
  // XCD-grouped bijective mapping (1024 blocks, 8 XCDs):
  // id = xcd + 8*j, j = panel*8 + col  ->  per-XCD stream walks the 8
  // column-blocks of each of its 16 row-panels consecutively.
  const int id = blockIdx.x;
  const int xcd = id & 7;
  const int j_ = id >> 3;                   // 0..127
  const int bxi = (xcd << 4) + (j_ >> 3);   // 0..127 row-panel
  const int byi = j_ & 7;                   // 0..7  col-block
  const int bm = bxi * 128;
  const int bn = byi * 128;
  const int wm = (w & 1) * 64;
  const int wn = (w >> 1) * 64;
  const int lm = lane & 15;
  const int lc = lane >> 4;  // 0..3

  f32x4 acc[4][4] = {};

  // fragment base pointers: row = (base + i*16 + lm), k-chunk = (kh*4+lc)*8
  const bf16_t* pa = A + (size_t)(bm + wm + lm) * DIM + lc * 8;
  const bf16_t* pb = W + (size_t)(bn + wn + lm) * DIM + lc * 8;

#pragma unroll 4
  for (int kt = 0; kt < DIM; kt += 64) {
    bf16x8 aF[4][2], bF[4][2];
#pragma unroll
    for (int i = 0; i < 4; ++i)
#pragma unroll
      for (int kh = 0; kh < 2; ++kh)
        aF[i][kh] =
            *(const bf16x8*)(pa + (size_t)i * 16 * DIM + kt + kh * 32);
#pragma unroll
    for (int j = 0; j < 4; ++j)
#pragma unroll
      for (int kh = 0; kh < 2; ++kh)
        bF[j][kh] =
            *(const bf16x8*)(pb + (size_t)j * 16 * DIM + kt + kh * 32);
#pragma unroll
    for (int i = 0; i < 4; ++i)
#pragma unroll
      for (int j = 0; j < 4; ++j)
#pragma unroll
        for (int kh = 0; kh < 2; ++kh)
          acc[i][j] = __builtin_amdgcn_mfma_f32_16x16x32_bf16(
              aF[i][kh], bF[j][kh], acc[i][j], 0, 0, 0);
  }

  // C/D layout: col = lane&15, row = (lane>>4)*4 + reg  [m89/m91]
  const int r0 = lc << 2;
#pragma unroll
  for (int i = 0; i < 4; ++i) {
    const int rowBase = bm + wm + i * 16 + r0;
    if constexpr (MODE == 0) {
      float s4[4];
#pragma unroll
      for (int r = 0; r < 4; ++r) s4[r] = scaleArr[rowBase + r];
#pragma unroll
      for (int j = 0; j < 4; ++j) {
        const int col = bn + wn + j * 16 + lm;
        const float bv = bias[col];
#pragma unroll
        for (int r = 0; r < 4; ++r)
          outB[(size_t)(rowBase + r) * DIM + col] =
              (bf16_t)fast_tanh(s4[r] * acc[i][j][r] + bv);
      }
    } else {
      f32x4 cf[4];
#pragma unroll
      for (int r = 0; r < 4; ++r) cf[r] = coef[rowBase + r];
      float ss[4] = {}, de[4] = {}, dc[4] = {}, dn[4] = {};
#pragma unroll
      for (int j = 0; j < 4; ++j) {
        const int col = bn + wn + j * 16 + lm;
        const f32x4 cp = colpack[col];  // {e, c, n, b2}
#pragma unroll
        for (int r = 0; r < 4; ++r) {
          const size_t idx = (size_t)(rowBase + r) * DIM + col;
          const float hp = (float)hbIn[idx];
          const float v = acc[i][j][r] + cp.w + cf[r].x * cp.x +
                          cf[r].y * cp.y + cf[r].z * cp.z + cf[r].w * hp;
          if constexpr (MODE == 1) outB[idx] = (bf16_t)v;
          if constexpr (MODE == 2) outF[idx] = v;
          ss[r] += v * v;
          de[r] += v * cp.x;
          dc[r] += v * cp.y;
          dn[r] += v * cp.z;
        }
      }
      // reduce each row's partials across the 16 lanes (lm) sharing it;
      // xor masks 1/2/4/8 stay within the lm group (lc bits untouched).
      // slot = byi*2 + (w>>1): column half wn=0 -> +0, wn=64 -> +1 (R4 fix).
      const int slot = byi * 2 + (w >> 1);
#pragma unroll
      for (int r = 0; r < 4; ++r) {
        float a = ss[r], b = de[r], c = dc[r], d = dn[r];
#pragma unroll
        for (int mask = 1; mask < 16; mask <<= 1) {
          a += __shfl_xor(a, mask);
          b += __shfl_xor(b, mask);
          c += __shfl_xor(c, mask);
          d += __shfl_xor(d, mask);
        }
        if (lm == 0) {
          f32x4 o;
          o.x = a; o.y = b; o.z = c; o.w = d;
          ((f32x4*)part)[(size_t)(rowBase + r) * 16 + slot] = o;
        }
      }
    }
  }
}

// ---------------------------------------------------------------------------
// convert: sum the 16 partials per row -> coef[row], scaleArr[row]
// (same math as the old stats tail, doClamp = 1). part[row][16] f32x4.
// ---------------------------------------------------------------------------
__global__ __launch_bounds__(256) void convert_kernel(
    const float* __restrict__ part, f32x4* __restrict__ coef,
    float* __restrict__ scaleArr) {
  const int row = blockIdx.x * 256 + threadIdx.x;
  const f32x4* p = (const f32x4*)part + (size_t)row * 16;
  float S = 0.f, E = 0.f, C = 0.f, N = 0.f;
#pragma unroll
  for (int b = 0; b < 16; ++b) {
    const f32x4 v = p[b];
    S += v.x; E += v.y; C += v.z; N += v.w;
  }
  const float norm = sqrtf(S);
  float scale = 1.f;
  if (norm > 10.f) scale = 10.f / (norm + 1e-8f);
  const float invn = 1.f / fmaxf(norm, 1e-12f);
  const float ae = E * invn;
  const float ac = C * invn;
  const float an = N * invn;
  const float nc = norm * scale;
  const float re = sqrtf(fmaxf(nc * nc - 2.f * nc * ae + 1.f, 0.f));
  const float rc = sqrtf(fmaxf(nc * nc - 2.f * nc * ac + 1.f, 0.f));
  const float rn = sqrtf(fmaxf(nc * nc - 2.f * nc * an + 1.f, 0.f));
  const float boundary = fminf(fmaxf(1.f - fabsf(ae - ac), 0.f), 1.f);
  f32x4 cf;
  cf.x = 0.1f * (1.f - ae) / fmaxf(re, 1e-12f);
  cf.y = 0.1f * (1.f - ac) / fmaxf(rc, 1e-12f);
  cf.z = (0.05f * (1.f - an) + 0.05f * boundary) / fmaxf(rn, 1e-12f);
  cf.w = scale * (1.f - cf.x - cf.y - cf.z);
  coef[row] = cf;
  scaleArr[row] = scale;
}

// ---------------------------------------------------------------------------
// Per-row stats for fp32 h0 (layer 0 only; also casts h0 -> hb bf16).
// ---------------------------------------------------------------------------
__global__ __launch_bounds__(256) void stats0_kernel(
    const float* __restrict__ src, bf16_t* __restrict__ dstb,
    float* __restrict__ scaleArr, f32x4* __restrict__ coef,
    const float* __restrict__ dirs) {
  const int row = blockIdx.x;
  const int t = threadIdx.x;
  const float4 v = ((const float4*)src)[(size_t)row * 256 + t];
  const float4 e = ((const float4*)dirs)[t];
  const float4 c = ((const float4*)dirs)[t + 256];
  const float4 n = ((const float4*)dirs)[t + 512];
  float ss = v.x * v.x + v.y * v.y + v.z * v.z + v.w * v.w;
  float de = v.x * e.x + v.y * e.y + v.z * e.z + v.w * e.w;
  float dc = v.x * c.x + v.y * c.y + v.z * c.z + v.w * c.w;
  float dn = v.x * n.x + v.y * n.y + v.z * n.z + v.w * n.w;
#pragma unroll
  for (int off = 32; off; off >>= 1) {
    ss += __shfl_down(ss, off);
    de += __shfl_down(de, off);
    dc += __shfl_down(dc, off);
    dn += __shfl_down(dn, off);
  }
  __shared__ float red[4][4];
  const int w = t >> 6;
  if ((t & 63) == 0) {
    red[w][0] = ss; red[w][1] = de; red[w][2] = dc; red[w][3] = dn;
  }
  __syncthreads();
  union { bf16_t b[4]; uint2 u; } pk;
  pk.b[0] = (bf16_t)v.x; pk.b[1] = (bf16_t)v.y;
  pk.b[2] = (bf16_t)v.z; pk.b[3] = (bf16_t)v.w;
  ((uint2*)dstb)[(size_t)row * 256 + t] = pk.u;
  if (t == 0) {
    float S = 0, E = 0, C = 0, N = 0;
#pragma unroll
    for (int i = 0; i < 4; ++i) {
      S += red[i][0]; E += red[i][1]; C += red[i][2]; N += red[i][3];
    }
    const float norm = sqrtf(S);
    const float scale = 1.f;  // no clamp on layer 0 input
    const float invn = 1.f / fmaxf(norm, 1e-12f);
    const float ae = E * invn;
    const float ac = C * invn;
    const float an = N * invn;
    const float nc = norm * scale;
    const float re = sqrtf(fmaxf(nc * nc - 2.f * nc * ae + 1.f, 0.f));
    const float rc = sqrtf(fmaxf(nc * nc - 2.f * nc * ac + 1.f, 0.f));
    const float rn = sqrtf(fmaxf(nc * nc - 2.f * nc * an + 1.f, 0.f));
    const float boundary = fminf(fmaxf(1.f - fabsf(ae - ac), 0.f), 1.f);
    f32x4 cf;
    cf.x = 0.1f * (1.f - ae) / fmaxf(re, 1e-12f);
    cf.y = 0.1f * (1.f - ac) / fmaxf(rc, 1e-12f);
    cf.z = (0.05f * (1.f - an) + 0.05f * boundary) / fmaxf(rn, 1e-12f);
    cf.w = scale * (1.f - cf.x - cf.y - cf.z);
    coef[row] = cf;
    scaleArr[row] = scale;
  }
}

__global__ __launch_bounds__(256) void finalize_kernel(
    float* __restrict__ outF, const float* __restrict__ scaleArr) {
  const int row = blockIdx.x;
  const int t = threadIdx.x;
  const float s = scaleArr[row];
  float4 v = ((float4*)outF)[(size_t)row * 256 + t];
  v.x *= s; v.y *= s; v.z *= s; v.w *= s;
  ((float4*)outF)[(size_t)row * 256 + t] = v;
}

// Normalize anchors -> dirs[3*DIM]
__global__ __launch_bounds__(256) void prep_dirs(
    const float* __restrict__ ae, const float* __restrict__ ac,
    const float* __restrict__ an, float* __restrict__ dirs) {
  const int t = threadIdx.x;
  const float4 a = ((const float4*)ae)[t];
  const float4 b = ((const float4*)ac)[t];
  const float4 c = ((const float4*)an)[t];
  float sa = a.x * a.x + a.y * a.y + a.z * a.z + a.w * a.w;
  float sb = b.x * b.x + b.y * b.y + b.z * b.z + b.w * b.w;
  float sc = c.x * c.x + c.y * c.y + c.z * c.z + c.w * c.w;
#pragma unroll
  for (int off = 32; off; off >>= 1) {
    sa += __shfl_down(sa, off);
    sb += __shfl_down(sb, off);
    sc += __shfl_down(sc, off);
  }
  __shared__ float red[4][3];
  __shared__ float fin[3];
  const int w = t >> 6;
  if ((t & 63) == 0) { red[w][0] = sa; red[w][1] = sb; red[w][2] = sc; }
  __syncthreads();
  if (t == 0) {
    float x = 0, y = 0, z = 0;
#pragma unroll
    for (int i = 0; i < 4; ++i) { x += red[i][0]; y += red[i][1]; z += red[i][2]; }
    fin[0] = x; fin[1] = y; fin[2] = z;
  }
  __syncthreads();
  const float ia = 1.f / fmaxf(sqrtf(fin[0]), 1e-12f);
  const float ib = 1.f / fmaxf(sqrtf(fin[1]), 1e-12f);
  const float ic = 1.f / fmaxf(sqrtf(fin[2]), 1e-12f);
  float4 oa, ob, oc;
  oa.x = a.x * ia; oa.y = a.y * ia; oa.z = a.z * ia; oa.w = a.w * ia;
  ob.x = b.x * ib; ob.y = b.y * ib; ob.z = b.z * ib; ob.w = b.w * ib;
  oc.x = c.x * ic; oc.y = c.y * ic; oc.z = c.z * ic; oc.w = c.w * ic;
  ((float4*)dirs)[t] = oa;
  ((float4*)dirs)[t + 256] = ob;
  ((float4*)dirs)[t + 512] = oc;
}

// Build colpack[col] = {e[col], c[col], n[col], b2[col]}
__global__ __launch_bounds__(256) void prep_cols(
    const float* __restrict__ dirs, const float* __restrict__ b2,
    f32x4* __restrict__ colpack) {
  const int t = threadIdx.x;  // handles cols 4t..4t+3
  const float4 e = ((const float4*)dirs)[t];
  const float4 c = ((const float4*)dirs)[t + 256];
  const float4 n = ((const float4*)dirs)[t + 512];
  const float4 b = ((const float4*)b2)[t];
  f32x4 o;
  o.x = e.x; o.y = c.x; o.z = n.x; o.w = b.x; colpack[4 * t + 0] = o;
  o.x = e.y; o.y = c.y; o.z = n.y; o.w = b.y; colpack[4 * t + 1] = o;
  o.x = e.z; o.y = c.z; o.z = n.z; o.w = b.z; colpack[4 * t + 2] = o;
  o.x = e.w; o.y = c.w; o.z = n.w; o.w = b.w; colpack[4 * t + 3] = o;
}

__global__ __launch_bounds__(256) void cast_w_kernel(
    const float* __restrict__ W, bf16_t* __restrict__ Wb) {
  const int i = blockIdx.x * 256 + threadIdx.x;
  const float4 v = ((const float4*)W)[i];
  union { bf16_t b[4]; uint2 u; } pk;
  pk.b[0] = (bf16_t)v.x; pk.b[1] = (bf16_t)v.y;
  pk.b[2] = (bf16_t)v.z; pk.b[3] = (bf16_t)v.w;
  ((uint2*)Wb)[i] = pk.u;
}

extern "C" void kernel_launch(void* const* d_in, const int* in_sizes, int n_in,
                              void* d_out, int out_size, void* d_ws,
                              size_t ws_size, hipStream_t stream) {
  const float* h0 = (const float*)d_in[0];
  const float* W1 = (const float*)d_in[1];
  const float* b1 = (const float*)d_in[2];
  const float* W2 = (const float*)d_in[3];
  const float* b2 = (const float*)d_in[4];
  const float* ae = (const float*)d_in[5];
  const float* ac = (const float*)d_in[6];
  const float* an = (const float*)d_in[7];
  float* outF = (float*)d_out;

  char* ws = (char*)d_ws;
  bf16_t* hb = (bf16_t*)ws;  ws += (size_t)BATCH * DIM * 2;   // 32 MB
  bf16_t* Tb = (bf16_t*)ws;  ws += (size_t)BATCH * DIM * 2;   // 32 MB
  bf16_t* W1b = (bf16_t*)ws; ws += (size_t)DIM * DIM * 2;     // 2 MB
  bf16_t* W2b = (bf16_t*)ws; ws += (size_t)DIM * DIM * 2;     // 2 MB
  float* dirs = (float*)ws;  ws += 3 * DIM * 4;
  f32x4* colpack = (f32x4*)ws; ws += DIM * 16;
  f32x4* coef = (f32x4*)ws;  ws += (size_t)BATCH * 16;
  float* scaleArr = (float*)ws; ws += (size_t)BATCH * 4;
  float* part = (float*)ws;  ws += (size_t)BATCH * 16 * 16;   // 4 MB

  prep_dirs<<<1, 256, 0, stream>>>(ae, ac, an, dirs);
  prep_cols<<<1, 256, 0, stream>>>(dirs, b2, colpack);
  cast_w_kernel<<<DIM * DIM / 1024, 256, 0, stream>>>(W1, W1b);
  cast_w_kernel<<<DIM * DIM / 1024, 256, 0, stream>>>(W2, W2b);
  stats0_kernel<<<BATCH, 256, 0, stream>>>(h0, hb, scaleArr, coef, dirs);

  const int grid = (BATCH / 128) * (DIM / 128);  // 1024 blocks, 1D
  for (int l = 0; l < NLAYER; ++l) {
    gemm_kernel<0><<<grid, 256, 0, stream>>>(hb, W1b, b1, Tb, nullptr, nullptr,
                                             nullptr, scaleArr, nullptr,
                                             nullptr);
    if (l < NLAYER - 1) {
      gemm_kernel<1><<<grid, 256, 0, stream>>>(Tb, W2b, b2, hb, nullptr, coef,
                                               colpack, nullptr, hb, part);
      convert_kernel<<<BATCH / 256, 256, 0, stream>>>(part, coef, scaleArr);
    } else {
      gemm_kernel<2><<<grid, 256, 0, stream>>>(Tb, W2b, b2, nullptr, outF, coef,
                                               colpack, nullptr, hb, part);
      convert_kernel<<<BATCH / 256, 256, 0, stream>>>(part, coef, scaleArr);
      finalize_kernel<<<BATCH, 256, 0, stream>>>(outF, scaleArr);
    }
  }
}

// Round 8
// 789.296 us; speedup vs baseline: 2.1341x; 2.1341x over previous
//
#include <hip/hip_runtime.h>
#include <hip/hip_bf16.h>
#include <math.h>

#define DIM 1024
#define BATCH 16384
#define NLAYER 6

typedef __bf16 bf16_t;
typedef __attribute__((ext_vector_type(8))) __bf16 bf16x8;
typedef __attribute__((ext_vector_type(4))) float f32x4;

__device__ __forceinline__ void gload16(const void* g, void* l) {
  __builtin_amdgcn_global_load_lds(
      (const __attribute__((address_space(1))) void*)g,
      (__attribute__((address_space(3))) void*)l, 16, 0, 0);
}

__device__ __forceinline__ float fast_tanh(float x) {
  x = fminf(9.f, fmaxf(-9.f, x));
  const float e = __expf(x + x);
  return (e - 1.f) * __builtin_amdgcn_rcpf(e + 1.f);
}

__device__ __forceinline__ float bf2f(unsigned short u) {
  return __uint_as_float(((unsigned int)u) << 16);
}

// ---------------------------------------------------------------------------
// GEMM: C[m,n] = sum_k A[m,k] * W[n,k]  (A [BATCH x DIM] bf16, W [DIM x DIM])
// MODE 0: Tb = bf16( fast_tanh(scale[m]*C + b1[n]) )
// MODE 1: hb = cf.w*hb_old + C + b2 + ce*e + cc*c + cn*nn  + fused row stats
// MODE 2: MODE1 math but writes fp32 outF ONLY (final layer; hb is dead)
//
// R8 K-loop: BK=32, DOUBLE-BUFFERED LDS (32KB total -> keeps 4 blocks/CU),
// depth-1 prefetch with COUNTED vmcnt(4) - never vmcnt(0) in the main loop.
// R0's stall was the per-tile __syncthreads vmcnt(0) drain (~900cy HBM
// latency, serial, aligned across blocks); here the wait targets loads
// issued a full tile earlier. R2's prefetch failed because it dropped to
// 1 block/CU; R7 cache-direct failed on raw latency (MfmaUtil 9.8%).
//
// LDS layout (per 128x32 tile): packed 128B rows - two 64-row half-tiles
// side by side: global row g, chunk c (8 bf16) stored at
//   row' = g&63,  log8 = (g>>6)*4 + c,  phys8 = log8 ^ (row'&7)
//   byte = row'*128 + phys8*16
// Same conflict-free XOR class as R0's proven BK=64 swizzle (0 conflicts).
// gload_lds dest is linear per wave (1KB = 8 rows'); the swizzle is applied
// on the per-lane GLOBAL source address (m173 pattern).
//
// Race audit: STAGE(t+1) writes buf[(t+1)&1], disjoint from buf[t&1] being
// read. vmcnt(4)+barrier#1 => all waves' tile-t loads landed before reads.
// barrier#2 (after MFMAs, which consume ds_reads via compiler lgkmcnt) =>
// no wave can issue iter-t+1 gloads (targeting buf[t&1]) while another
// still reads it. sched_barrier(0) pins each region (rule 18/m201).
// R3 lesson: no global atomics. R4 lesson: part slot = byi*2+(w>>1).
// ---------------------------------------------------------------------------
template <int MODE>
__global__ __launch_bounds__(256, 4) void gemm_kernel(
    const bf16_t* __restrict__ A, const bf16_t* __restrict__ W,
    const float* __restrict__ bias, bf16_t* __restrict__ outB,
    float* __restrict__ outF, const f32x4* __restrict__ coef,
    const f32x4* __restrict__ colpack, const float* __restrict__ scaleArr,
    const bf16_t* __restrict__ hbIn, float* __restrict__ part) {
  __shared__ __align__(16) bf16_t sA[2][128 * 32];
  __shared__ __align__(16) bf16_t sB[2][128 * 32];
  const int tid = threadIdx.x;
  const int w = tid >> 6;
  const int lane = tid & 63;
  const int bm = blockIdx.x * 128;
  const int bn = blockIdx.y * 128;
  const int byi = blockIdx.y;
  const int wm = (w & 1) * 64;
  const int wn = (w >> 1) * 64;
  const int lm = lane & 15;
  const int lc = lane >> 4;  // 0..3

  f32x4 acc[4][4] = {};

  // ---- staging thread mapping ----
  // wave w, round rnd in {0,1}: covers rows' 8w+(lane>>3) + rnd*32,
  // phys chunk = lane&7; content log8 = phys ^ rp  (rp = lane>>3, row'&7 = rp)
  const int rp = lane >> 3;        // 0..7
  const int phys = lane & 7;
  const int log8 = phys ^ rp;      // 0..7
  const int ghalf = log8 >> 2;     // +64 global rows
  const int gch = log8 & 3;        // chunk (8 bf16) within the 32-k tile
  const int rowp0 = 8 * w + rp;    // rnd-0 row'
  const bf16_t* gA0 = A + (size_t)(bm + rowp0 + ghalf * 64) * DIM + gch * 8;
  const bf16_t* gW0 = W + (size_t)(bn + rowp0 + ghalf * 64) * DIM + gch * 8;

#define STAGE(buf, koff)                                                   \
  {                                                                        \
    char* dA_ = (char*)&sA[(buf)][0] + w * 1024;                           \
    char* dB_ = (char*)&sB[(buf)][0] + w * 1024;                           \
    gload16(gA0 + (koff), dA_);                                            \
    gload16(gA0 + (koff) + (size_t)32 * DIM, dA_ + 4096);                  \
    gload16(gW0 + (koff), dB_);                                            \
    gload16(gW0 + (koff) + (size_t)32 * DIM, dB_ + 4096);                  \
  }

  // ---- reader offsets ----
  // aF[i]: g = wm + i*16 + lm -> row' = i*16+lm, log8 = (wm>>6)*4+lc,
  //        phys = log8 ^ (lm&7); byte = (i*16+lm)*128 + phys*16 ( +i*2048 )
  const int aOff = lm * 128 + (((((wm >> 6) << 2) + lc) ^ (lm & 7)) << 4);
  const int bOff = lm * 128 + (((((wn >> 6) << 2) + lc) ^ (lm & 7)) << 4);

#define TILE_COMPUTE(buf)                                                  \
  {                                                                        \
    const char* cA_ = (const char*)&sA[(buf)][0];                          \
    const char* cB_ = (const char*)&sB[(buf)][0];                          \
    bf16x8 aF[4], bF[4];                                                   \
    _Pragma("unroll") for (int i = 0; i < 4; ++i)                          \
        aF[i] = *(const bf16x8*)(cA_ + aOff + i * 2048);                   \
    _Pragma("unroll") for (int j = 0; j < 4; ++j)                          \
        bF[j] = *(const bf16x8*)(cB_ + bOff + j * 2048);                   \
    _Pragma("unroll") for (int i = 0; i < 4; ++i)                          \
        _Pragma("unroll") for (int j = 0; j < 4; ++j) acc[i][j] =          \
            __builtin_amdgcn_mfma_f32_16x16x32_bf16(aF[i], bF[j],          \
                                                    acc[i][j], 0, 0, 0);   \
  }

  // prologue: tile 0 -> buf 0
  STAGE(0, 0);
  for (int t = 0; t < 31; ++t) {
    STAGE((t + 1) & 1, (t + 1) * 32);       // prefetch next tile
    asm volatile("s_waitcnt vmcnt(4)" ::: "memory");  // tile-t loads done
    __builtin_amdgcn_sched_barrier(0);
    __builtin_amdgcn_s_barrier();           // all waves staged tile t
    __builtin_amdgcn_sched_barrier(0);
    TILE_COMPUTE(t & 1);
    __builtin_amdgcn_sched_barrier(0);
    __builtin_amdgcn_s_barrier();           // reads done before overwrite
    __builtin_amdgcn_sched_barrier(0);
  }
  // peeled last tile (31) in buf 1
  asm volatile("s_waitcnt vmcnt(0)" ::: "memory");
  __builtin_amdgcn_sched_barrier(0);
  __builtin_amdgcn_s_barrier();
  __builtin_amdgcn_sched_barrier(0);
  TILE_COMPUTE(1);
#undef STAGE
#undef TILE_COMPUTE

  // ---- epilogue (R5 verbatim) ----
  // C/D layout: col = lane&15, row = (lane>>4)*4 + reg  [m89/m91]
  const int r0 = lc << 2;
#pragma unroll
  for (int i = 0; i < 4; ++i) {
    const int rowBase = bm + wm + i * 16 + r0;
    if constexpr (MODE == 0) {
      float s4[4];
#pragma unroll
      for (int r = 0; r < 4; ++r) s4[r] = scaleArr[rowBase + r];
#pragma unroll
      for (int j = 0; j < 4; ++j) {
        const int col = bn + wn + j * 16 + lm;
        const float bv = bias[col];
#pragma unroll
        for (int r = 0; r < 4; ++r)
          outB[(size_t)(rowBase + r) * DIM + col] =
              (bf16_t)fast_tanh(s4[r] * acc[i][j][r] + bv);
      }
    } else {
      f32x4 cf[4];
#pragma unroll
      for (int r = 0; r < 4; ++r) cf[r] = coef[rowBase + r];
      float ss[4] = {}, de[4] = {}, dc[4] = {}, dn[4] = {};
#pragma unroll
      for (int j = 0; j < 4; ++j) {
        const int col = bn + wn + j * 16 + lm;
        const f32x4 cp = colpack[col];  // {e, c, n, b2}
#pragma unroll
        for (int r = 0; r < 4; ++r) {
          const size_t idx = (size_t)(rowBase + r) * DIM + col;
          const float hp = (float)hbIn[idx];
          const float v = acc[i][j][r] + cp.w + cf[r].x * cp.x +
                          cf[r].y * cp.y + cf[r].z * cp.z + cf[r].w * hp;
          if constexpr (MODE == 1) outB[idx] = (bf16_t)v;
          if constexpr (MODE == 2) outF[idx] = v;
          ss[r] += v * v;
          de[r] += v * cp.x;
          dc[r] += v * cp.y;
          dn[r] += v * cp.z;
        }
      }
      // 16-lane (lm) reduction; masks 1/2/4/8 stay within the lm group.
      const int slot = byi * 2 + (w >> 1);
#pragma unroll
      for (int r = 0; r < 4; ++r) {
        float a = ss[r], b = de[r], c = dc[r], d = dn[r];
#pragma unroll
        for (int mask = 1; mask < 16; mask <<= 1) {
          a += __shfl_xor(a, mask);
          b += __shfl_xor(b, mask);
          c += __shfl_xor(c, mask);
          d += __shfl_xor(d, mask);
        }
        if (lm == 0) {
          f32x4 o;
          o.x = a; o.y = b; o.z = c; o.w = d;
          ((f32x4*)part)[(size_t)(rowBase + r) * 16 + slot] = o;
        }
      }
    }
  }
}

// ---------------------------------------------------------------------------
// convert: sum the 16 partials per row -> coef[row], scaleArr[row]
// ---------------------------------------------------------------------------
__global__ __launch_bounds__(256) void convert_kernel(
    const float* __restrict__ part, f32x4* __restrict__ coef,
    float* __restrict__ scaleArr) {
  const int row = blockIdx.x * 256 + threadIdx.x;
  const f32x4* p = (const f32x4*)part + (size_t)row * 16;
  float S = 0.f, E = 0.f, C = 0.f, N = 0.f;
#pragma unroll
  for (int b = 0; b < 16; ++b) {
    const f32x4 v = p[b];
    S += v.x; E += v.y; C += v.z; N += v.w;
  }
  const float norm = sqrtf(S);
  float scale = 1.f;
  if (norm > 10.f) scale = 10.f / (norm + 1e-8f);
  const float invn = 1.f / fmaxf(norm, 1e-12f);
  const float ae = E * invn;
  const float ac = C * invn;
  const float an = N * invn;
  const float nc = norm * scale;
  const float re = sqrtf(fmaxf(nc * nc - 2.f * nc * ae + 1.f, 0.f));
  const float rc = sqrtf(fmaxf(nc * nc - 2.f * nc * ac + 1.f, 0.f));
  const float rn = sqrtf(fmaxf(nc * nc - 2.f * nc * an + 1.f, 0.f));
  const float boundary = fminf(fmaxf(1.f - fabsf(ae - ac), 0.f), 1.f);
  f32x4 cf;
  cf.x = 0.1f * (1.f - ae) / fmaxf(re, 1e-12f);
  cf.y = 0.1f * (1.f - ac) / fmaxf(rc, 1e-12f);
  cf.z = (0.05f * (1.f - an) + 0.05f * boundary) / fmaxf(rn, 1e-12f);
  cf.w = scale * (1.f - cf.x - cf.y - cf.z);
  coef[row] = cf;
  scaleArr[row] = scale;
}

// ---------------------------------------------------------------------------
// Per-row stats for fp32 h0 (layer 0 only; also casts h0 -> hb bf16).
// ---------------------------------------------------------------------------
__global__ __launch_bounds__(256) void stats0_kernel(
    const float* __restrict__ src, bf16_t* __restrict__ dstb,
    float* __restrict__ scaleArr, f32x4* __restrict__ coef,
    const float* __restrict__ dirs) {
  const int row = blockIdx.x;
  const int t = threadIdx.x;
  const float4 v = ((const float4*)src)[(size_t)row * 256 + t];
  const float4 e = ((const float4*)dirs)[t];
  const float4 c = ((const float4*)dirs)[t + 256];
  const float4 n = ((const float4*)dirs)[t + 512];
  float ss = v.x * v.x + v.y * v.y + v.z * v.z + v.w * v.w;
  float de = v.x * e.x + v.y * e.y + v.z * e.z + v.w * e.w;
  float dc = v.x * c.x + v.y * c.y + v.z * c.z + v.w * c.w;
  float dn = v.x * n.x + v.y * n.y + v.z * n.z + v.w * n.w;
#pragma unroll
  for (int off = 32; off; off >>= 1) {
    ss += __shfl_down(ss, off);
    de += __shfl_down(de, off);
    dc += __shfl_down(dc, off);
    dn += __shfl_down(dn, off);
  }
  __shared__ float red[4][4];
  const int w = t >> 6;
  if ((t & 63) == 0) {
    red[w][0] = ss; red[w][1] = de; red[w][2] = dc; red[w][3] = dn;
  }
  __syncthreads();
  union { bf16_t b[4]; uint2 u; } pk;
  pk.b[0] = (bf16_t)v.x; pk.b[1] = (bf16_t)v.y;
  pk.b[2] = (bf16_t)v.z; pk.b[3] = (bf16_t)v.w;
  ((uint2*)dstb)[(size_t)row * 256 + t] = pk.u;
  if (t == 0) {
    float S = 0, E = 0, C = 0, N = 0;
#pragma unroll
    for (int i = 0; i < 4; ++i) {
      S += red[i][0]; E += red[i][1]; C += red[i][2]; N += red[i][3];
    }
    const float norm = sqrtf(S);
    const float scale = 1.f;  // no clamp on layer 0 input
    const float invn = 1.f / fmaxf(norm, 1e-12f);
    const float ae = E * invn;
    const float ac = C * invn;
    const float an = N * invn;
    const float nc = norm * scale;
    const float re = sqrtf(fmaxf(nc * nc - 2.f * nc * ae + 1.f, 0.f));
    const float rc = sqrtf(fmaxf(nc * nc - 2.f * nc * ac + 1.f, 0.f));
    const float rn = sqrtf(fmaxf(nc * nc - 2.f * nc * an + 1.f, 0.f));
    const float boundary = fminf(fmaxf(1.f - fabsf(ae - ac), 0.f), 1.f);
    f32x4 cf;
    cf.x = 0.1f * (1.f - ae) / fmaxf(re, 1e-12f);
    cf.y = 0.1f * (1.f - ac) / fmaxf(rc, 1e-12f);
    cf.z = (0.05f * (1.f - an) + 0.05f * boundary) / fmaxf(rn, 1e-12f);
    cf.w = scale * (1.f - cf.x - cf.y - cf.z);
    coef[row] = cf;
    scaleArr[row] = scale;
  }
}

__global__ __launch_bounds__(256) void finalize_kernel(
    float* __restrict__ outF, const float* __restrict__ scaleArr) {
  const int row = blockIdx.x;
  const int t = threadIdx.x;
  const float s = scaleArr[row];
  float4 v = ((float4*)outF)[(size_t)row * 256 + t];
  v.x *= s; v.y *= s; v.z *= s; v.w *= s;
  ((float4*)outF)[(size_t)row * 256 + t] = v;
}

// Normalize anchors -> dirs[3*DIM]
__global__ __launch_bounds__(256) void prep_dirs(
    const float* __restrict__ ae, const float* __restrict__ ac,
    const float* __restrict__ an, float* __restrict__ dirs) {
  const int t = threadIdx.x;
  const float4 a = ((const float4*)ae)[t];
  const float4 b = ((const float4*)ac)[t];
  const float4 c = ((const float4*)an)[t];
  float sa = a.x * a.x + a.y * a.y + a.z * a.z + a.w * a.w;
  float sb = b.x * b.x + b.y * b.y + b.z * b.z + b.w * b.w;
  float sc = c.x * c.x + c.y * c.y + c.z * c.z + c.w * c.w;
#pragma unroll
  for (int off = 32; off; off >>= 1) {
    sa += __shfl_down(sa, off);
    sb += __shfl_down(sb, off);
    sc += __shfl_down(sc, off);
  }
  __shared__ float red[4][3];
  __shared__ float fin[3];
  const int w = t >> 6;
  if ((t & 63) == 0) { red[w][0] = sa; red[w][1] = sb; red[w][2] = sc; }
  __syncthreads();
  if (t == 0) {
    float x = 0, y = 0, z = 0;
#pragma unroll
    for (int i = 0; i < 4; ++i) { x += red[i][0]; y += red[i][1]; z += red[i][2]; }
    fin[0] = x; fin[1] = y; fin[2] = z;
  }
  __syncthreads();
  const float ia = 1.f / fmaxf(sqrtf(fin[0]), 1e-12f);
  const float ib = 1.f / fmaxf(sqrtf(fin[1]), 1e-12f);
  const float ic = 1.f / fmaxf(sqrtf(fin[2]), 1e-12f);
  float4 oa, ob, oc;
  oa.x = a.x * ia; oa.y = a.y * ia; oa.z = a.z * ia; oa.w = a.w * ia;
  ob.x = b.x * ib; ob.y = b.y * ib; ob.z = b.z * ib; ob.w = b.w * ib;
  oc.x = c.x * ic; oc.y = c.y * ic; oc.z = c.z * ic; oc.w = c.w * ic;
  ((float4*)dirs)[t] = oa;
  ((float4*)dirs)[t + 256] = ob;
  ((float4*)dirs)[t + 512] = oc;
}

// Build colpack[col] = {e[col], c[col], n[col], b2[col]}
__global__ __launch_bounds__(256) void prep_cols(
    const float* __restrict__ dirs, const float* __restrict__ b2,
    f32x4* __restrict__ colpack) {
  const int t = threadIdx.x;  // handles cols 4t..4t+3
  const float4 e = ((const float4*)dirs)[t];
  const float4 c = ((const float4*)dirs)[t + 256];
  const float4 n = ((const float4*)dirs)[t + 512];
  const float4 b = ((const float4*)b2)[t];
  f32x4 o;
  o.x = e.x; o.y = c.x; o.z = n.x; o.w = b.x; colpack[4 * t + 0] = o;
  o.x = e.y; o.y = c.y; o.z = n.y; o.w = b.y; colpack[4 * t + 1] = o;
  o.x = e.z; o.y = c.z; o.z = n.z; o.w = b.z; colpack[4 * t + 2] = o;
  o.x = e.w; o.y = c.w; o.z = n.w; o.w = b.w; colpack[4 * t + 3] = o;
}

__global__ __launch_bounds__(256) void cast_w_kernel(
    const float* __restrict__ W, bf16_t* __restrict__ Wb) {
  const int i = blockIdx.x * 256 + threadIdx.x;
  const float4 v = ((const float4*)W)[i];
  union { bf16_t b[4]; uint2 u; } pk;
  pk.b[0] = (bf16_t)v.x; pk.b[1] = (bf16_t)v.y;
  pk.b[2] = (bf16_t)v.z; pk.b[3] = (bf16_t)v.w;
  ((uint2*)Wb)[i] = pk.u;
}

extern "C" void kernel_launch(void* const* d_in, const int* in_sizes, int n_in,
                              void* d_out, int out_size, void* d_ws,
                              size_t ws_size, hipStream_t stream) {
  const float* h0 = (const float*)d_in[0];
  const float* W1 = (const float*)d_in[1];
  const float* b1 = (const float*)d_in[2];
  const float* W2 = (const float*)d_in[3];
  const float* b2 = (const float*)d_in[4];
  const float* ae = (const float*)d_in[5];
  const float* ac = (const float*)d_in[6];
  const float* an = (const float*)d_in[7];
  float* outF = (float*)d_out;

  char* ws = (char*)d_ws;
  bf16_t* hb = (bf16_t*)ws;  ws += (size_t)BATCH * DIM * 2;   // 32 MB
  bf16_t* Tb = (bf16_t*)ws;  ws += (size_t)BATCH * DIM * 2;   // 32 MB
  bf16_t* W1b = (bf16_t*)ws; ws += (size_t)DIM * DIM * 2;     // 2 MB
  bf16_t* W2b = (bf16_t*)ws; ws += (size_t)DIM * DIM * 2;     // 2 MB
  float* dirs = (float*)ws;  ws += 3 * DIM * 4;
  f32x4* colpack = (f32x4*)ws; ws += DIM * 16;
  f32x4* coef = (f32x4*)ws;  ws += (size_t)BATCH * 16;
  float* scaleArr = (float*)ws; ws += (size_t)BATCH * 4;
  float* part = (float*)ws;  ws += (size_t)BATCH * 16 * 16;   // 4 MB

  prep_dirs<<<1, 256, 0, stream>>>(ae, ac, an, dirs);
  prep_cols<<<1, 256, 0, stream>>>(dirs, b2, colpack);
  cast_w_kernel<<<DIM * DIM / 1024, 256, 0, stream>>>(W1, W1b);
  cast_w_kernel<<<DIM * DIM / 1024, 256, 0, stream>>>(W2, W2b);
  stats0_kernel<<<BATCH, 256, 0, stream>>>(h0, hb, scaleArr, coef, dirs);

  dim3 grid(BATCH / 128, DIM / 128);
  for (int l = 0; l < NLAYER; ++l) {
    gemm_kernel<0><<<grid, 256, 0, stream>>>(hb, W1b, b1, Tb, nullptr, nullptr,
                                             nullptr, scaleArr, nullptr,
                                             nullptr);
    if (l < NLAYER - 1) {
      gemm_kernel<1><<<grid, 256, 0, stream>>>(Tb, W2b, b2, hb, nullptr, coef,
                                               colpack, nullptr, hb, part);
      convert_kernel<<<BATCH / 256, 256, 0, stream>>>(part, coef, scaleArr);
    } else {
      gemm_kernel<2><<<grid, 256, 0, stream>>>(Tb, W2b, b2, nullptr, outF, coef,
                                               colpack, nullptr, hb, part);
      convert_kernel<<<BATCH / 256, 256, 0, stream>>>(part, coef, scaleArr);
      finalize_kernel<<<BATCH, 256, 0, stream>>>(outF, scaleArr);
    }
  }
}

// Round 10
// 688.767 us; speedup vs baseline: 2.4455x; 1.1460x over previous
//
#include <hip/hip_runtime.h>
#include <hip/hip_bf16.h>
#include <math.h>

#define DIM 1024
#define BATCH 16384
#define NLAYER 6

typedef __bf16 bf16_t;
typedef __attribute__((ext_vector_type(8))) __bf16 bf16x8;
typedef __attribute__((ext_vector_type(4))) float f32x4;

__device__ __forceinline__ void gload16(const void* g, void* l) {
  __builtin_amdgcn_global_load_lds(
      (const __attribute__((address_space(1))) void*)g,
      (__attribute__((address_space(3))) void*)l, 16, 0, 0);
}

__device__ __forceinline__ float fast_tanh(float x) {
  x = fminf(9.f, fmaxf(-9.f, x));
  const float e = __expf(x + x);
  return (e - 1.f) * __builtin_amdgcn_rcpf(e + 1.f);
}

__device__ __forceinline__ float bf2f(unsigned short u) {
  return __uint_as_float(((unsigned int)u) << 16);
}

// ---------------------------------------------------------------------------
// 8-PHASE 256x256 GEMM (m201 template port).  C[m,n] = sum_k A[m,k]*W[n,k].
// MODE 0: Tb = bf16(tanh(scale*C + b1));  MODE 1: hb update + fused stats;
// MODE 2: MODE1 math -> fp32 outF only.
//
// 512 thr / 8 waves (wm = w>>2 in {0,1} row-half, wn = w&3 col-quarter).
// Per-wave output 128x64 = acc[8][4].  BK=64.  Grid (64,4) = 256 = 1/CU.
// LDS 128KB: Ah[buf][half] = buf*32768 + half*16384 (half = 128 rows x 64k);
//            Bh[buf][half] = 65536 + same.  K-tile t lives in buf t&1.
// Wave reads ONLY Ah[.][wm] and Bh[.][wn>>1] (B once per K-tile, phase 0,
// held in regs).  Phase q: {if q==0: 8 B-reads} + 4 A-reads + stage 1
// half-tile (2 gload16/thread) + barrier + lgkmcnt(0) + setprio(1) +
// 16 MFMA + setprio(0) + [vmcnt] + barrier.
//
// Stage schedule per iteration i (K-tiles 2i,2i+1), target dead-regions:
//   ph0:A1h0(2i+1) ph1:A1h1(2i+1) ph2:B0h0(2i+2) ph3:B0h1(2i+2)
//   ph4:A0h0(2i+2) ph5:A0h1(2i+2) ph6:B1h0(2i+3) ph7:B1h1(2i+3)
// vmcnt(4) at ph3/ph7 ONLY: oldest-8-complete = exactly the 4 half-tiles
// the next phase-group consumes (audited: steady state, prologue, tail).
// Loop i=0..6 unconditional (max k-index 15); i=7 peeled: stages only
// A1(15) in ph0-1, vmcnt(0) at ph3, no further stages.
// LDS XOR swizzle: phys_chunk = logical ^ (row&7), via pre-swizzled global
// source (gload_lds dest linear, m173).  Same conflict-free class as R0.
// R3: no atomics.  R4: part slot per (byi,wn) writer: slot = byi*4 + wn.
// ---------------------------------------------------------------------------
template <int MODE>
__global__ __launch_bounds__(512, 2) void gemm_kernel(
    const bf16_t* __restrict__ A, const bf16_t* __restrict__ W,
    const float* __restrict__ bias, bf16_t* __restrict__ outB,
    float* __restrict__ outF, const f32x4* __restrict__ coef,
    const f32x4* __restrict__ colpack, const float* __restrict__ scaleArr,
    const bf16_t* __restrict__ hbIn, float* __restrict__ part) {
  __shared__ __align__(16) char smem[131072];
  const int tid = threadIdx.x;
  const int w = tid >> 6;     // 0..7
  const int lane = tid & 63;
  const int bm = blockIdx.x * 256;
  const int bn = blockIdx.y * 256;
  const int byi = blockIdx.y;  // 0..3
  const int wm = w >> 2;       // row half
  const int wn = w & 3;        // col quarter
  const int lm = lane & 15;
  const int lc = lane >> 4;    // 0..3

  f32x4 acc[8][4] = {};
  bf16x8 Bf[4][2];

  // staging: thread covers rows (w*16 + g*8 + (lane>>3)) of a 128-row half,
  // phys chunk lane&7, content chunk = phys ^ (row&7)  (row&7 = (lane>>3)&7)
  const int srow = lane >> 3;
  const int swzl = ((lane & 7) ^ (srow & 7)) * 8;
  const bf16_t* stA = A + (size_t)(bm + w * 16 + srow) * DIM + swzl;
  const bf16_t* stB = W + (size_t)(bn + w * 16 + srow) * DIM + swzl;

  // reader offsets: row-in-half = f*16+lm (A) / (wn&1)*64+j*16+lm (B),
  // byte = row*128 + ((kh*4+lc)^(row&7))*16  (row&7 == lm&7 here)
  int chOff[2];
  chOff[0] = ((lc) ^ (lm & 7)) << 4;
  chOff[1] = ((4 + lc) ^ (lm & 7)) << 4;
  const int aBase0 = wm * 16384 + lm * 128;
  const int bBase0 = 65536 + (wn >> 1) * 16384 + (wn & 1) * 8192 + lm * 128;

#define STA(buf, half, ko)                                                  \
  {                                                                         \
    gload16(stA + (size_t)((half)*128) * DIM + (ko),                        \
            smem + (buf)*32768 + (half)*16384 + w * 2048);                  \
    gload16(stA + (size_t)((half)*128 + 8) * DIM + (ko),                    \
            smem + (buf)*32768 + (half)*16384 + w * 2048 + 1024);           \
  }
#define STB(buf, half, ko)                                                  \
  {                                                                         \
    gload16(stB + (size_t)((half)*128) * DIM + (ko),                        \
            smem + 65536 + (buf)*32768 + (half)*16384 + w * 2048);          \
    gload16(stB + (size_t)((half)*128 + 8) * DIM + (ko),                    \
            smem + 65536 + (buf)*32768 + (half)*16384 + w * 2048 + 1024);   \
  }
#define RDA(buf, f, kh) \
  (*(const bf16x8*)(smem + (buf)*32768 + aBase0 + (f)*2048 + chOff[kh]))
#define RDB(buf, j, kh) \
  (*(const bf16x8*)(smem + (buf)*32768 + bBase0 + (j)*2048 + chOff[kh]))

#define PH(buf, q, STG, VM)                                                 \
  {                                                                         \
    if ((q) == 0) {                                                         \
      _Pragma("unroll") for (int j = 0; j < 4; ++j) {                       \
        Bf[j][0] = RDB(buf, j, 0);                                          \
        Bf[j][1] = RDB(buf, j, 1);                                          \
      }                                                                     \
    }                                                                       \
    bf16x8 aA[2][2];                                                        \
    aA[0][0] = RDA(buf, 2 * (q), 0);                                        \
    aA[0][1] = RDA(buf, 2 * (q), 1);                                        \
    aA[1][0] = RDA(buf, 2 * (q) + 1, 0);                                    \
    aA[1][1] = RDA(buf, 2 * (q) + 1, 1);                                    \
    STG;                                                                    \
    __builtin_amdgcn_sched_barrier(0);                                      \
    __builtin_amdgcn_s_barrier();                                           \
    asm volatile("s_waitcnt lgkmcnt(0)" ::: "memory");                      \
    __builtin_amdgcn_sched_barrier(0);                                      \
    __builtin_amdgcn_s_setprio(1);                                          \
    _Pragma("unroll") for (int s = 0; s < 2; ++s)                           \
        _Pragma("unroll") for (int j = 0; j < 4; ++j)                       \
            _Pragma("unroll") for (int kh = 0; kh < 2; ++kh)                \
                acc[2 * (q) + s][j] =                                       \
        __builtin_amdgcn_mfma_f32_16x16x32_bf16(aA[s][kh], Bf[j][kh],       \
                                                acc[2 * (q) + s][j], 0, 0,  \
                                                0);                         \
    __builtin_amdgcn_s_setprio(0);                                          \
    VM;                                                                     \
    __builtin_amdgcn_sched_barrier(0);                                      \
    __builtin_amdgcn_s_barrier();                                           \
  }

  // prologue: A(0), B(0), B(1); vmcnt(4) leaves B(1)'s 4 loads in flight
  STA(0, 0, 0);
  STA(0, 1, 0);
  STB(0, 0, 0);
  STB(0, 1, 0);
  STB(1, 0, 64);
  STB(1, 1, 64);
  asm volatile("s_waitcnt vmcnt(4)" ::: "memory");
  __builtin_amdgcn_s_barrier();

#pragma unroll 1
  for (int i = 0; i < 7; ++i) {
    const int kA1 = (2 * i + 1) * 64;
    const int kN = (2 * i + 2) * 64;
    const int kB1 = (2 * i + 3) * 64;
    PH(0, 0, STA(1, 0, kA1), )
    PH(0, 1, STA(1, 1, kA1), )
    PH(0, 2, STB(0, 0, kN), )
    PH(0, 3, STB(0, 1, kN),
       asm volatile("s_waitcnt vmcnt(4)" ::: "memory"))
    PH(1, 0, STA(0, 0, kN), )
    PH(1, 1, STA(0, 1, kN), )
    PH(1, 2, STB(1, 0, kB1), )
    PH(1, 3, STB(1, 1, kB1),
       asm volatile("s_waitcnt vmcnt(4)" ::: "memory"))
  }
  // peeled i=7: K-tiles 14 (buf0, already staged) and 15 (buf1: A staged
  // here, B staged in i=6 ph6-7).  vmcnt(0) before the buf1 phases.
  PH(0, 0, STA(1, 0, 15 * 64), )
  PH(0, 1, STA(1, 1, 15 * 64), )
  PH(0, 2, , )
  PH(0, 3, , asm volatile("s_waitcnt vmcnt(0)" ::: "memory"))
  PH(1, 0, , )
  PH(1, 1, , )
  PH(1, 2, , )
  PH(1, 3, , )

#undef STA
#undef STB
#undef RDA
#undef RDB
#undef PH

  // ---- epilogue ----
  // C/D layout: col = lane&15, row = (lane>>4)*4 + reg  [m89/m91]
  const int r0 = lc << 2;
#pragma unroll
  for (int f = 0; f < 8; ++f) {
    const int rowBase = bm + wm * 128 + f * 16 + r0;
    if constexpr (MODE == 0) {
      float s4[4];
#pragma unroll
      for (int r = 0; r < 4; ++r) s4[r] = scaleArr[rowBase + r];
#pragma unroll
      for (int j = 0; j < 4; ++j) {
        const int col = bn + wn * 64 + j * 16 + lm;
        const float bv = bias[col];
#pragma unroll
        for (int r = 0; r < 4; ++r)
          outB[(size_t)(rowBase + r) * DIM + col] =
              (bf16_t)fast_tanh(s4[r] * acc[f][j][r] + bv);
      }
    } else {
      f32x4 cf[4];
#pragma unroll
      for (int r = 0; r < 4; ++r) cf[r] = coef[rowBase + r];
      float ss[4] = {}, de[4] = {}, dc[4] = {}, dn[4] = {};
#pragma unroll
      for (int j = 0; j < 4; ++j) {
        const int col = bn + wn * 64 + j * 16 + lm;
        const f32x4 cp = colpack[col];  // {e, c, n, b2}
#pragma unroll
        for (int r = 0; r < 4; ++r) {
          const size_t idx = (size_t)(rowBase + r) * DIM + col;
          const float hp = (float)hbIn[idx];
          const float v = acc[f][j][r] + cp.w + cf[r].x * cp.x +
                          cf[r].y * cp.y + cf[r].z * cp.z + cf[r].w * hp;
          if constexpr (MODE == 1) outB[idx] = (bf16_t)v;
          if constexpr (MODE == 2) outF[idx] = v;
          ss[r] += v * v;
          de[r] += v * cp.x;
          dc[r] += v * cp.y;
          dn[r] += v * cp.z;
        }
      }
      // reduce across the 16 lanes (lm) sharing each row; writers per row:
      // 4 waves (wn) x 4 col-blocks (byi) -> slot = byi*4 + wn (16 slots).
      const int slot = byi * 4 + wn;
#pragma unroll
      for (int r = 0; r < 4; ++r) {
        float a = ss[r], b = de[r], c = dc[r], d = dn[r];
#pragma unroll
        for (int mask = 1; mask < 16; mask <<= 1) {
          a += __shfl_xor(a, mask);
          b += __shfl_xor(b, mask);
          c += __shfl_xor(c, mask);
          d += __shfl_xor(d, mask);
        }
        if (lm == 0) {
          f32x4 o;
          o.x = a; o.y = b; o.z = c; o.w = d;
          ((f32x4*)part)[(size_t)(rowBase + r) * 16 + slot] = o;
        }
      }
    }
  }
}

// ---------------------------------------------------------------------------
// convert: sum the 16 partials per row -> coef[row], scaleArr[row]
// ---------------------------------------------------------------------------
__global__ __launch_bounds__(256) void convert_kernel(
    const float* __restrict__ part, f32x4* __restrict__ coef,
    float* __restrict__ scaleArr) {
  const int row = blockIdx.x * 256 + threadIdx.x;
  const f32x4* p = (const f32x4*)part + (size_t)row * 16;
  float S = 0.f, E = 0.f, C = 0.f, N = 0.f;
#pragma unroll
  for (int b = 0; b < 16; ++b) {
    const f32x4 v = p[b];
    S += v.x; E += v.y; C += v.z; N += v.w;
  }
  const float norm = sqrtf(S);
  float scale = 1.f;
  if (norm > 10.f) scale = 10.f / (norm + 1e-8f);
  const float invn = 1.f / fmaxf(norm, 1e-12f);
  const float ae = E * invn;
  const float ac = C * invn;
  const float an = N * invn;
  const float nc = norm * scale;
  const float re = sqrtf(fmaxf(nc * nc - 2.f * nc * ae + 1.f, 0.f));
  const float rc = sqrtf(fmaxf(nc * nc - 2.f * nc * ac + 1.f, 0.f));
  const float rn = sqrtf(fmaxf(nc * nc - 2.f * nc * an + 1.f, 0.f));
  const float boundary = fminf(fmaxf(1.f - fabsf(ae - ac), 0.f), 1.f);
  f32x4 cf;
  cf.x = 0.1f * (1.f - ae) / fmaxf(re, 1e-12f);
  cf.y = 0.1f * (1.f - ac) / fmaxf(rc, 1e-12f);
  cf.z = (0.05f * (1.f - an) + 0.05f * boundary) / fmaxf(rn, 1e-12f);
  cf.w = scale * (1.f - cf.x - cf.y - cf.z);
  coef[row] = cf;
  scaleArr[row] = scale;
}

// ---------------------------------------------------------------------------
// Per-row stats for fp32 h0 (layer 0 only; also casts h0 -> hb bf16).
// ---------------------------------------------------------------------------
__global__ __launch_bounds__(256) void stats0_kernel(
    const float* __restrict__ src, bf16_t* __restrict__ dstb,
    float* __restrict__ scaleArr, f32x4* __restrict__ coef,
    const float* __restrict__ dirs) {
  const int row = blockIdx.x;
  const int t = threadIdx.x;
  const float4 v = ((const float4*)src)[(size_t)row * 256 + t];
  const float4 e = ((const float4*)dirs)[t];
  const float4 c = ((const float4*)dirs)[t + 256];
  const float4 n = ((const float4*)dirs)[t + 512];
  float ss = v.x * v.x + v.y * v.y + v.z * v.z + v.w * v.w;
  float de = v.x * e.x + v.y * e.y + v.z * e.z + v.w * e.w;
  float dc = v.x * c.x + v.y * c.y + v.z * c.z + v.w * c.w;
  float dn = v.x * n.x + v.y * n.y + v.z * n.z + v.w * n.w;
#pragma unroll
  for (int off = 32; off; off >>= 1) {
    ss += __shfl_down(ss, off);
    de += __shfl_down(de, off);
    dc += __shfl_down(dc, off);
    dn += __shfl_down(dn, off);
  }
  __shared__ float red[4][4];
  const int w = t >> 6;
  if ((t & 63) == 0) {
    red[w][0] = ss; red[w][1] = de; red[w][2] = dc; red[w][3] = dn;
  }
  __syncthreads();
  union { bf16_t b[4]; uint2 u; } pk;
  pk.b[0] = (bf16_t)v.x; pk.b[1] = (bf16_t)v.y;
  pk.b[2] = (bf16_t)v.z; pk.b[3] = (bf16_t)v.w;
  ((uint2*)dstb)[(size_t)row * 256 + t] = pk.u;
  if (t == 0) {
    float S = 0, E = 0, C = 0, N = 0;
#pragma unroll
    for (int i = 0; i < 4; ++i) {
      S += red[i][0]; E += red[i][1]; C += red[i][2]; N += red[i][3];
    }
    const float norm = sqrtf(S);
    const float scale = 1.f;  // no clamp on layer 0 input
    const float invn = 1.f / fmaxf(norm, 1e-12f);
    const float ae = E * invn;
    const float ac = C * invn;
    const float an = N * invn;
    const float nc = norm * scale;
    const float re = sqrtf(fmaxf(nc * nc - 2.f * nc * ae + 1.f, 0.f));
    const float rc = sqrtf(fmaxf(nc * nc - 2.f * nc * ac + 1.f, 0.f));
    const float rn = sqrtf(fmaxf(nc * nc - 2.f * nc * an + 1.f, 0.f));
    const float boundary = fminf(fmaxf(1.f - fabsf(ae - ac), 0.f), 1.f);
    f32x4 cf;
    cf.x = 0.1f * (1.f - ae) / fmaxf(re, 1e-12f);
    cf.y = 0.1f * (1.f - ac) / fmaxf(rc, 1e-12f);
    cf.z = (0.05f * (1.f - an) + 0.05f * boundary) / fmaxf(rn, 1e-12f);
    cf.w = scale * (1.f - cf.x - cf.y - cf.z);
    coef[row] = cf;
    scaleArr[row] = scale;
  }
}

__global__ __launch_bounds__(256) void finalize_kernel(
    float* __restrict__ outF, const float* __restrict__ scaleArr) {
  const int row = blockIdx.x;
  const int t = threadIdx.x;
  const float s = scaleArr[row];
  float4 v = ((float4*)outF)[(size_t)row * 256 + t];
  v.x *= s; v.y *= s; v.z *= s; v.w *= s;
  ((float4*)outF)[(size_t)row * 256 + t] = v;
}

// Normalize anchors -> dirs[3*DIM]
__global__ __launch_bounds__(256) void prep_dirs(
    const float* __restrict__ ae, const float* __restrict__ ac,
    const float* __restrict__ an, float* __restrict__ dirs) {
  const int t = threadIdx.x;
  const float4 a = ((const float4*)ae)[t];
  const float4 b = ((const float4*)ac)[t];
  const float4 c = ((const float4*)an)[t];
  float sa = a.x * a.x + a.y * a.y + a.z * a.z + a.w * a.w;
  float sb = b.x * b.x + b.y * b.y + b.z * b.z + b.w * b.w;
  float sc = c.x * c.x + c.y * c.y + c.z * c.z + c.w * c.w;
#pragma unroll
  for (int off = 32; off; off >>= 1) {
    sa += __shfl_down(sa, off);
    sb += __shfl_down(sb, off);
    sc += __shfl_down(sc, off);
  }
  __shared__ float red[4][3];
  __shared__ float fin[3];
  const int w = t >> 6;
  if ((t & 63) == 0) { red[w][0] = sa; red[w][1] = sb; red[w][2] = sc; }
  __syncthreads();
  if (t == 0) {
    float x = 0, y = 0, z = 0;
#pragma unroll
    for (int i = 0; i < 4; ++i) { x += red[i][0]; y += red[i][1]; z += red[i][2]; }
    fin[0] = x; fin[1] = y; fin[2] = z;
  }
  __syncthreads();
  const float ia = 1.f / fmaxf(sqrtf(fin[0]), 1e-12f);
  const float ib = 1.f / fmaxf(sqrtf(fin[1]), 1e-12f);
  const float ic = 1.f / fmaxf(sqrtf(fin[2]), 1e-12f);
  float4 oa, ob, oc;
  oa.x = a.x * ia; oa.y = a.y * ia; oa.z = a.z * ia; oa.w = a.w * ia;
  ob.x = b.x * ib; ob.y = b.y * ib; ob.z = b.z * ib; ob.w = b.w * ib;
  oc.x = c.x * ic; oc.y = c.y * ic; oc.z = c.z * ic; oc.w = c.w * ic;
  ((float4*)dirs)[t] = oa;
  ((float4*)dirs)[t + 256] = ob;
  ((float4*)dirs)[t + 512] = oc;
}

// Build colpack[col] = {e[col], c[col], n[col], b2[col]}
__global__ __launch_bounds__(256) void prep_cols(
    const float* __restrict__ dirs, const float* __restrict__ b2,
    f32x4* __restrict__ colpack) {
  const int t = threadIdx.x;  // handles cols 4t..4t+3
  const float4 e = ((const float4*)dirs)[t];
  const float4 c = ((const float4*)dirs)[t + 256];
  const float4 n = ((const float4*)dirs)[t + 512];
  const float4 b = ((const float4*)b2)[t];
  f32x4 o;
  o.x = e.x; o.y = c.x; o.z = n.x; o.w = b.x; colpack[4 * t + 0] = o;
  o.x = e.y; o.y = c.y; o.z = n.y; o.w = b.y; colpack[4 * t + 1] = o;
  o.x = e.z; o.y = c.z; o.z = n.z; o.w = b.z; colpack[4 * t + 2] = o;
  o.x = e.w; o.y = c.w; o.z = n.w; o.w = b.w; colpack[4 * t + 3] = o;
}

__global__ __launch_bounds__(256) void cast_w_kernel(
    const float* __restrict__ W, bf16_t* __restrict__ Wb) {
  const int i = blockIdx.x * 256 + threadIdx.x;
  const float4 v = ((const float4*)W)[i];
  union { bf16_t b[4]; uint2 u; } pk;
  pk.b[0] = (bf16_t)v.x; pk.b[1] = (bf16_t)v.y;
  pk.b[2] = (bf16_t)v.z; pk.b[3] = (bf16_t)v.w;
  ((uint2*)Wb)[i] = pk.u;
}

extern "C" void kernel_launch(void* const* d_in, const int* in_sizes, int n_in,
                              void* d_out, int out_size, void* d_ws,
                              size_t ws_size, hipStream_t stream) {
  const float* h0 = (const float*)d_in[0];
  const float* W1 = (const float*)d_in[1];
  const float* b1 = (const float*)d_in[2];
  const float* W2 = (const float*)d_in[3];
  const float* b2 = (const float*)d_in[4];
  const float* ae = (const float*)d_in[5];
  const float* ac = (const float*)d_in[6];
  const float* an = (const float*)d_in[7];
  float* outF = (float*)d_out;

  char* ws = (char*)d_ws;
  bf16_t* hb = (bf16_t*)ws;  ws += (size_t)BATCH * DIM * 2;   // 32 MB
  bf16_t* Tb = (bf16_t*)ws;  ws += (size_t)BATCH * DIM * 2;   // 32 MB
  bf16_t* W1b = (bf16_t*)ws; ws += (size_t)DIM * DIM * 2;     // 2 MB
  bf16_t* W2b = (bf16_t*)ws; ws += (size_t)DIM * DIM * 2;     // 2 MB
  float* dirs = (float*)ws;  ws += 3 * DIM * 4;
  f32x4* colpack = (f32x4*)ws; ws += DIM * 16;
  f32x4* coef = (f32x4*)ws;  ws += (size_t)BATCH * 16;
  float* scaleArr = (float*)ws; ws += (size_t)BATCH * 4;
  float* part = (float*)ws;  ws += (size_t)BATCH * 16 * 16;   // 4 MB

  prep_dirs<<<1, 256, 0, stream>>>(ae, ac, an, dirs);
  prep_cols<<<1, 256, 0, stream>>>(dirs, b2, colpack);
  cast_w_kernel<<<DIM * DIM / 1024, 256, 0, stream>>>(W1, W1b);
  cast_w_kernel<<<DIM * DIM / 1024, 256, 0, stream>>>(W2, W2b);
  stats0_kernel<<<BATCH, 256, 0, stream>>>(h0, hb, scaleArr, coef, dirs);

  dim3 grid(BATCH / 256, DIM / 256);
  for (int l = 0; l < NLAYER; ++l) {
    gemm_kernel<0><<<grid, 512, 0, stream>>>(hb, W1b, b1, Tb, nullptr, nullptr,
                                             nullptr, scaleArr, nullptr,
                                             nullptr);
    if (l < NLAYER - 1) {
      gemm_kernel<1><<<grid, 512, 0, stream>>>(Tb, W2b, b2, hb, nullptr, coef,
                                               colpack, nullptr, hb, part);
      convert_kernel<<<BATCH / 256, 256, 0, stream>>>(part, coef, scaleArr);
    } else {
      gemm_kernel<2><<<grid, 512, 0, stream>>>(Tb, W2b, b2, nullptr, outF, coef,
                                               colpack, nullptr, hb, part);
      convert_kernel<<<BATCH / 256, 256, 0, stream>>>(part, coef, scaleArr);
      finalize_kernel<<<BATCH, 256, 0, stream>>>(outF, scaleArr);
    }
  }
}